// Round 8
// baseline (452.775 us; speedup 1.0000x reference)
//
#include <hip/hip_runtime.h>

#define NN 8192
#define FIN 512
#define FOUT 64
#define LRELU_ALPHA 0.2f
#define LOG2E 1.4426950408889634f
#define TS 132   // adj LDS tile row stride in ints (128 + 4 pad -> bank spread)

typedef __attribute__((ext_vector_type(4))) float f32x4;
typedef __attribute__((ext_vector_type(4))) int i32x4;
typedef __attribute__((ext_vector_type(8))) __bf16 bf16x8;
typedef __attribute__((ext_vector_type(4))) __bf16 bf16x4;

#if __has_builtin(__builtin_amdgcn_exp2f)
#define EXP2F(x) __builtin_amdgcn_exp2f(x)
#else
#define EXP2F(x) exp2f(x)
#endif

// Kernel A: round-4 verbatim + one extra store: s2log[row] = s2[row]*log2e
// (lets attn drop its 32 KB LDS mirror of s2 and read the premultiplied
// values straight from L2).
__global__ __launch_bounds__(256) void gat_wh(
    const float* __restrict__ x, const float* __restrict__ W,
    const float* __restrict__ A,
    __bf16* __restrict__ WhbT, float* __restrict__ s1, float* __restrict__ s2,
    float* __restrict__ s2log)
{
    const int wid  = (blockIdx.x * 256 + threadIdx.x) >> 6;
    const int lane = threadIdx.x & 63;
    const int cg   = lane & 15;
    const int kh   = lane >> 4;
    const int row0 = wid * 4;

    f32x4 acc[4];
    #pragma unroll
    for (int r_ = 0; r_ < 4; ++r_) acc[r_] = (f32x4){0.f, 0.f, 0.f, 0.f};

    const float* xb   = x + (size_t)row0 * FIN + kh * 128;
    const float* wcol = W + cg * 4 + (size_t)kh * 128 * FOUT;

    #pragma unroll 2
    for (int k = 0; k < 128; k += 4) {
        f32x4 wv[4];
        #pragma unroll
        for (int u = 0; u < 4; ++u)
            wv[u] = *reinterpret_cast<const f32x4*>(wcol + (size_t)(k + u) * FOUT);
        #pragma unroll
        for (int r_ = 0; r_ < 4; ++r_) {
            f32x4 xv = *reinterpret_cast<const f32x4*>(xb + (size_t)r_ * FIN + k);
            acc[r_] += xv[0] * wv[0];
            acc[r_] += xv[1] * wv[1];
            acc[r_] += xv[2] * wv[2];
            acc[r_] += xv[3] * wv[3];
        }
    }

    #pragma unroll
    for (int r_ = 0; r_ < 4; ++r_) {
        #pragma unroll
        for (int u = 0; u < 4; ++u) {
            acc[r_][u] += __shfl_xor(acc[r_][u], 16);
            acc[r_][u] += __shfl_xor(acc[r_][u], 32);
        }
    }

    f32x4 a1v = *reinterpret_cast<const f32x4*>(A + cg * 4);
    f32x4 a2v = *reinterpret_cast<const f32x4*>(A + FOUT + cg * 4);
    #pragma unroll
    for (int r_ = 0; r_ < 4; ++r_) {
        float s1p = acc[r_][0]*a1v[0] + acc[r_][1]*a1v[1] + acc[r_][2]*a1v[2] + acc[r_][3]*a1v[3];
        float s2p = acc[r_][0]*a2v[0] + acc[r_][1]*a2v[1] + acc[r_][2]*a2v[2] + acc[r_][3]*a2v[3];
        #pragma unroll
        for (int off = 1; off < 16; off <<= 1) {
            s1p += __shfl_xor(s1p, off);
            s2p += __shfl_xor(s2p, off);
        }
        if (lane == 0) {
            s1[row0 + r_] = s1p;
            s2[row0 + r_] = s2p;
            s2log[row0 + r_] = s2p * LOG2E;
        }
    }

    if (kh == 0) {
        #pragma unroll
        for (int u = 0; u < 4; ++u) {
            bf16x4 pk;
            pk[0] = (__bf16)acc[0][u];
            pk[1] = (__bf16)acc[1][u];
            pk[2] = (__bf16)acc[2][u];
            pk[3] = (__bf16)acc[3][u];
            *reinterpret_cast<bf16x4*>(WhbT + (size_t)(cg * 4 + u) * NN + row0) = pk;
        }
    }
}

// Kernel B: round-4 arithmetic VERBATIM. Single structural change: adj is
// staged through wave-private LDS tiles with COALESCED loads. Direct loads
// issued 16 scattered 64B transactions per instr (16 rows @ 32KB stride,
// 128B/row/iter -> ~55% DRAM efficiency, insensitive to occupancy [R3] and
// in-flight depth [R7]). Staged: each instr reads 1KB contiguous (2 rows x
// 512B), 4x coarser bursts; MFMA-layout reads then hit LDS (wave-private,
// no barrier; 2-lane/bank -> conflict-free).
__global__ __launch_bounds__(256) void gat_attn(
    const int* __restrict__ adj, const __bf16* __restrict__ WhbT,
    const float* __restrict__ s1g, const float* __restrict__ s2log,
    const float* __restrict__ bias, float* __restrict__ out)
{
    __shared__ int  adjt[4][16][TS];      // 33 KB: per-wave 16x128 adj tile
    __shared__ float red[4];
    __shared__ float ol[4][16];
    __shared__ float oacc[4][16][FOUT];

    const int tid  = threadIdx.x;
    const int w    = tid >> 6;
    const int lane = tid & 63;
    const int r    = lane & 15;           // MFMA A-row / C-col
    const int q    = lane >> 4;           // k-chunk q*8..q*8+7
    const int row0 = blockIdx.x * 16;

    // global max of s2log (premultiplied by log2e in gat_wh)
    float mx = -3.0e38f;
    for (int i = tid; i < NN / 4; i += 256) {
        f32x4 v = reinterpret_cast<const f32x4*>(s2log)[i];
        mx = fmaxf(mx, fmaxf(fmaxf(v[0], v[1]), fmaxf(v[2], v[3])));
    }
    #pragma unroll
    for (int off = 1; off < 64; off <<= 1)
        mx = fmaxf(mx, __shfl_xor(mx, off));
    if (lane == 0) red[w] = mx;
    __syncthreads();
    const float s2maxl = fmaxf(fmaxf(red[0], red[1]), fmaxf(red[2], red[3]));

    const float s1l = s1g[row0 + r] * LOG2E;
    const float tM  = s1l + s2maxl;
    const float Ml  = fmaxf(tM, LRELU_ALPHA * tM);   // lrelu in log2 domain
    const float c1  = s1l - Ml;
    const float c2  = LRELU_ALPHA * s1l - Ml;

    float l = 0.f;
    f32x4 acc0 = {0,0,0,0}, acc1 = {0,0,0,0}, acc2 = {0,0,0,0}, acc3 = {0,0,0,0};

    // staging addresses: instr i covers rows 2i+(lane>>5), 512B contiguous/row
    const int srow  = lane >> 5;          // 0..1
    const int scol  = (lane & 31) << 2;   // 0,4,...,124 (ints)
    const int* adjs = adj + (size_t)(row0 + srow) * NN + (w << 11) + scol;

    const __bf16* wpb  = WhbT + (w << 11) + (q << 3);
    const __bf16* wp0  = wpb + (size_t)(0 * 16 + r) * NN;
    const __bf16* wp1  = wpb + (size_t)(1 * 16 + r) * NN;
    const __bf16* wp2  = wpb + (size_t)(2 * 16 + r) * NN;
    const __bf16* wp3  = wpb + (size_t)(3 * 16 + r) * NN;
    const float*  s2p_ = s2log + (w << 11) + (q << 3);

    for (int it = 0; it < 16; ++it) {                 // 128 cols per iteration
        const int c0 = it << 7;

        // coalesced stage: 8 instrs x 1KB contiguous -> wave-private LDS
        #pragma unroll
        for (int i = 0; i < 8; ++i) {
            i32x4 v = *reinterpret_cast<const i32x4*>(adjs + (size_t)(2 * i) * NN + c0);
            *reinterpret_cast<i32x4*>(&adjt[w][2 * i + srow][scol]) = v;
        }

        #pragma unroll
        for (int h = 0; h < 4; ++h) {                 // 32 cols per half
            const int jc = c0 + (h << 5);
            i32x4 av0 = *reinterpret_cast<const i32x4*>(&adjt[w][r][(h << 5) + (q << 3)]);
            i32x4 av1 = *reinterpret_cast<const i32x4*>(&adjt[w][r][(h << 5) + (q << 3) + 4]);
            bf16x8 b0 = *reinterpret_cast<const bf16x8*>(wp0 + jc);
            bf16x8 b1 = *reinterpret_cast<const bf16x8*>(wp1 + jc);
            bf16x8 b2 = *reinterpret_cast<const bf16x8*>(wp2 + jc);
            bf16x8 b3 = *reinterpret_cast<const bf16x8*>(wp3 + jc);
            f32x4 s2a = *reinterpret_cast<const f32x4*>(s2p_ + jc);
            f32x4 s2c = *reinterpret_cast<const f32x4*>(s2p_ + jc + 4);

            bf16x8 af;
            float ps = 0.f;
            #pragma unroll
            for (int i = 0; i < 4; ++i) {
                float g0 = fmaxf(c1 + s2a[i], fmaf(LRELU_ALPHA, s2a[i], c2));
                g0 = (av0[i] > 0) ? g0 : -3.0e38f;     // masked -> exp2 -> 0
                float p0 = EXP2F(g0);
                ps += p0;
                af[i] = (__bf16)p0;
                float g1 = fmaxf(c1 + s2c[i], fmaf(LRELU_ALPHA, s2c[i], c2));
                g1 = (av1[i] > 0) ? g1 : -3.0e38f;
                float p1 = EXP2F(g1);
                ps += p1;
                af[i + 4] = (__bf16)p1;
            }
            l += ps;
            acc0 = __builtin_amdgcn_mfma_f32_16x16x32_bf16(af, b0, acc0, 0, 0, 0);
            acc1 = __builtin_amdgcn_mfma_f32_16x16x32_bf16(af, b1, acc1, 0, 0, 0);
            acc2 = __builtin_amdgcn_mfma_f32_16x16x32_bf16(af, b2, acc2, 0, 0, 0);
            acc3 = __builtin_amdgcn_mfma_f32_16x16x32_bf16(af, b3, acc3, 0, 0, 0);
        }
    }

    l += __shfl_xor(l, 16);
    l += __shfl_xor(l, 32);
    if (lane < 16) ol[w][lane] = l;
    #pragma unroll
    for (int reg = 0; reg < 4; ++reg) {
        oacc[w][(q << 2) + reg][0 * 16 + r] = acc0[reg];
        oacc[w][(q << 2) + reg][1 * 16 + r] = acc1[reg];
        oacc[w][(q << 2) + reg][2 * 16 + r] = acc2[reg];
        oacc[w][(q << 2) + reg][3 * 16 + r] = acc3[reg];
    }
    __syncthreads();

    for (int o = tid; o < 16 * FOUT; o += 256) {
        const int rr = o >> 6;
        const int f  = o & 63;
        const float L = ol[0][rr] + ol[1][rr] + ol[2][rr] + ol[3][rr];
        const float O = oacc[0][rr][f] + oacc[1][rr][f] + oacc[2][rr][f] + oacc[3][rr][f];
        out[(size_t)(row0 + rr) * FOUT + f] = O / L + bias[f];
    }
}

extern "C" void kernel_launch(void* const* d_in, const int* in_sizes, int n_in,
                              void* d_out, int out_size, void* d_ws, size_t ws_size,
                              hipStream_t stream)
{
    const float* x    = (const float*)d_in[0];
    const int*   adj  = (const int*)d_in[1];
    const float* W    = (const float*)d_in[2];
    const float* bias = (const float*)d_in[3];
    const float* A    = (const float*)d_in[4];
    float* out = (float*)d_out;

    // workspace: WhbT (1 MB) | s1 (32 KB) | s2 (32 KB) | s2log (32 KB)
    char* ws = (char*)d_ws;
    __bf16* WhbT  = (__bf16*)ws;
    float*  s1    = (float*)(ws + (size_t)FOUT * NN * sizeof(__bf16));
    float*  s2    = s1 + NN;
    float*  s2log = s2 + NN;

    gat_wh<<<dim3(512), dim3(256), 0, stream>>>(x, W, A, WhbT, s1, s2, s2log);
    gat_attn<<<dim3(NN / 16), dim3(256), 0, stream>>>(adj, WhbT, s1, s2log, bias, out);
}

// Round 9
// 408.842 us; speedup vs baseline: 1.1075x; 1.1075x over previous
//
#include <hip/hip_runtime.h>

#define NN 8192
#define FIN 512
#define FOUT 64
#define LRELU_ALPHA 0.2f
#define LOG2E 1.4426950408889634f

typedef __attribute__((ext_vector_type(4))) float f32x4;
typedef __attribute__((ext_vector_type(4))) int i32x4;
typedef __attribute__((ext_vector_type(8))) __bf16 bf16x8;
typedef __attribute__((ext_vector_type(4))) __bf16 bf16x4;

#if __has_builtin(__builtin_amdgcn_exp2f)
#define EXP2F(x) __builtin_amdgcn_exp2f(x)
#else
#define EXP2F(x) exp2f(x)
#endif

// Kernel A: VERBATIM round-4 (409.2 µs build; ~L2/VALU floor).
// 4 rows/wave: one W fetch feeds 4 FMAs; W L2 traffic 256 MB; x read once.
__global__ __launch_bounds__(256) void gat_wh(
    const float* __restrict__ x, const float* __restrict__ W,
    const float* __restrict__ A,
    __bf16* __restrict__ WhbT, float* __restrict__ s1, float* __restrict__ s2)
{
    const int wid  = (blockIdx.x * 256 + threadIdx.x) >> 6;
    const int lane = threadIdx.x & 63;
    const int cg   = lane & 15;
    const int kh   = lane >> 4;
    const int row0 = wid * 4;

    f32x4 acc[4];
    #pragma unroll
    for (int r_ = 0; r_ < 4; ++r_) acc[r_] = (f32x4){0.f, 0.f, 0.f, 0.f};

    const float* xb   = x + (size_t)row0 * FIN + kh * 128;
    const float* wcol = W + cg * 4 + (size_t)kh * 128 * FOUT;

    #pragma unroll 2
    for (int k = 0; k < 128; k += 4) {
        f32x4 wv[4];
        #pragma unroll
        for (int u = 0; u < 4; ++u)
            wv[u] = *reinterpret_cast<const f32x4*>(wcol + (size_t)(k + u) * FOUT);
        #pragma unroll
        for (int r_ = 0; r_ < 4; ++r_) {
            f32x4 xv = *reinterpret_cast<const f32x4*>(xb + (size_t)r_ * FIN + k);
            acc[r_] += xv[0] * wv[0];
            acc[r_] += xv[1] * wv[1];
            acc[r_] += xv[2] * wv[2];
            acc[r_] += xv[3] * wv[3];
        }
    }

    #pragma unroll
    for (int r_ = 0; r_ < 4; ++r_) {
        #pragma unroll
        for (int u = 0; u < 4; ++u) {
            acc[r_][u] += __shfl_xor(acc[r_][u], 16);
            acc[r_][u] += __shfl_xor(acc[r_][u], 32);
        }
    }

    f32x4 a1v = *reinterpret_cast<const f32x4*>(A + cg * 4);
    f32x4 a2v = *reinterpret_cast<const f32x4*>(A + FOUT + cg * 4);
    #pragma unroll
    for (int r_ = 0; r_ < 4; ++r_) {
        float s1p = acc[r_][0]*a1v[0] + acc[r_][1]*a1v[1] + acc[r_][2]*a1v[2] + acc[r_][3]*a1v[3];
        float s2p = acc[r_][0]*a2v[0] + acc[r_][1]*a2v[1] + acc[r_][2]*a2v[2] + acc[r_][3]*a2v[3];
        #pragma unroll
        for (int off = 1; off < 16; off <<= 1) {
            s1p += __shfl_xor(s1p, off);
            s2p += __shfl_xor(s2p, off);
        }
        if (lane == 0) { s1[row0 + r_] = s1p; s2[row0 + r_] = s2p; }
    }

    if (kh == 0) {
        #pragma unroll
        for (int u = 0; u < 4; ++u) {
            bf16x4 pk;
            pk[0] = (__bf16)acc[0][u];
            pk[1] = (__bf16)acc[1][u];
            pk[2] = (__bf16)acc[2][u];
            pk[3] = (__bf16)acc[3][u];
            *reinterpret_cast<bf16x4*>(WhbT + (size_t)(cg * 4 + u) * NN + row0) = pk;
        }
    }
}

// Kernel B: round-4 structure VERBATIM (direct loads, 32 iters x 2 halves,
// fixed-M + c1/c2 fold). SINGLE delta vs the 409.2 µs build: the row-sum l
// is accumulated by a 5th MFMA against an all-ones B operand (matrix pipe is
// ~2% utilized -> free) instead of 9 scalar VALU adds per half + an end
// shuffle-reduce. B == 1.0 everywhere is fragment-layout-proof; accL's C
// layout (row = q*4+reg) matches acc0's, as already used by the oacc writes.
__global__ __launch_bounds__(256) void gat_attn(
    const int* __restrict__ adj, const __bf16* __restrict__ WhbT,
    const float* __restrict__ s1g, const float* __restrict__ s2g,
    const float* __restrict__ bias, float* __restrict__ out)
{
    __shared__ float s2l[NN];             // s2 * log2(e)
    __shared__ float red[4];
    __shared__ float ol[4][16];
    __shared__ float oacc[4][16][FOUT];

    const int tid  = threadIdx.x;
    const int w    = tid >> 6;
    const int lane = tid & 63;
    const int r    = lane & 15;           // MFMA A-row / C-col
    const int q    = lane >> 4;           // k-chunk q*8..q*8+7
    const int row0 = blockIdx.x * 16;

    float mx = -3.0e38f;
    for (int i = tid; i < NN / 4; i += 256) {
        f32x4 v = reinterpret_cast<const f32x4*>(s2g)[i];
        v *= LOG2E;
        reinterpret_cast<f32x4*>(s2l)[i] = v;
        mx = fmaxf(mx, fmaxf(fmaxf(v[0], v[1]), fmaxf(v[2], v[3])));
    }
    #pragma unroll
    for (int off = 1; off < 64; off <<= 1)
        mx = fmaxf(mx, __shfl_xor(mx, off));
    if (lane == 0) red[w] = mx;
    __syncthreads();
    const float s2maxl = fmaxf(fmaxf(red[0], red[1]), fmaxf(red[2], red[3]));

    const float s1l = s1g[row0 + r] * LOG2E;
    const float tM  = s1l + s2maxl;
    const float Ml  = fmaxf(tM, LRELU_ALPHA * tM);   // lrelu in log2 domain
    const float c1  = s1l - Ml;
    const float c2  = LRELU_ALPHA * s1l - Ml;

    const __bf16 oneb = (__bf16)1.0f;
    const bf16x8 onesv = {oneb, oneb, oneb, oneb, oneb, oneb, oneb, oneb};

    f32x4 acc0 = {0,0,0,0}, acc1 = {0,0,0,0}, acc2 = {0,0,0,0}, acc3 = {0,0,0,0};
    f32x4 accL = {0,0,0,0};

    const int*    adjp = adj + (size_t)(row0 + r) * NN + (w << 11) + (q << 3);
    const __bf16* wpb  = WhbT + (w << 11) + (q << 3);
    const __bf16* wp0  = wpb + (size_t)(0 * 16 + r) * NN;
    const __bf16* wp1  = wpb + (size_t)(1 * 16 + r) * NN;
    const __bf16* wp2  = wpb + (size_t)(2 * 16 + r) * NN;
    const __bf16* wp3  = wpb + (size_t)(3 * 16 + r) * NN;
    const float*  s2p_ = s2l + (w << 11) + (q << 3);

    for (int it = 0; it < 32; ++it) {                 // 64 cols per iteration
        const int j0 = it << 6;
        #pragma unroll
        for (int c = 0; c < 2; ++c) {
            const int jc = j0 + (c << 5);
            i32x4 av0 = *reinterpret_cast<const i32x4*>(adjp + jc);
            i32x4 av1 = *reinterpret_cast<const i32x4*>(adjp + jc + 4);
            bf16x8 b0 = *reinterpret_cast<const bf16x8*>(wp0 + jc);
            bf16x8 b1 = *reinterpret_cast<const bf16x8*>(wp1 + jc);
            bf16x8 b2 = *reinterpret_cast<const bf16x8*>(wp2 + jc);
            bf16x8 b3 = *reinterpret_cast<const bf16x8*>(wp3 + jc);
            f32x4 s2a = *reinterpret_cast<const f32x4*>(s2p_ + jc);
            f32x4 s2c = *reinterpret_cast<const f32x4*>(s2p_ + jc + 4);

            bf16x8 af;
            #pragma unroll
            for (int i = 0; i < 4; ++i) {
                float g0 = fmaxf(c1 + s2a[i], fmaf(LRELU_ALPHA, s2a[i], c2));
                g0 = (av0[i] > 0) ? g0 : -3.0e38f;     // masked -> exp2 -> 0
                af[i] = (__bf16)EXP2F(g0);
                float g1 = fmaxf(c1 + s2c[i], fmaf(LRELU_ALPHA, s2c[i], c2));
                g1 = (av1[i] > 0) ? g1 : -3.0e38f;
                af[i + 4] = (__bf16)EXP2F(g1);
            }
            acc0 = __builtin_amdgcn_mfma_f32_16x16x32_bf16(af, b0, acc0, 0, 0, 0);
            acc1 = __builtin_amdgcn_mfma_f32_16x16x32_bf16(af, b1, acc1, 0, 0, 0);
            acc2 = __builtin_amdgcn_mfma_f32_16x16x32_bf16(af, b2, acc2, 0, 0, 0);
            acc3 = __builtin_amdgcn_mfma_f32_16x16x32_bf16(af, b3, acc3, 0, 0, 0);
            accL = __builtin_amdgcn_mfma_f32_16x16x32_bf16(af, onesv, accL, 0, 0, 0);
        }
    }

    // l lives in accL: C row = q*4+reg, identical across cols (B uniform)
    if (r == 0) {
        #pragma unroll
        for (int reg = 0; reg < 4; ++reg) ol[w][(q << 2) + reg] = accL[reg];
    }
    #pragma unroll
    for (int reg = 0; reg < 4; ++reg) {
        oacc[w][(q << 2) + reg][0 * 16 + r] = acc0[reg];
        oacc[w][(q << 2) + reg][1 * 16 + r] = acc1[reg];
        oacc[w][(q << 2) + reg][2 * 16 + r] = acc2[reg];
        oacc[w][(q << 2) + reg][3 * 16 + r] = acc3[reg];
    }
    __syncthreads();

    for (int o = tid; o < 16 * FOUT; o += 256) {
        const int rr = o >> 6;
        const int f  = o & 63;
        const float L = ol[0][rr] + ol[1][rr] + ol[2][rr] + ol[3][rr];
        const float O = oacc[0][rr][f] + oacc[1][rr][f] + oacc[2][rr][f] + oacc[3][rr][f];
        out[(size_t)(row0 + rr) * FOUT + f] = O / L + bias[f];
    }
}

extern "C" void kernel_launch(void* const* d_in, const int* in_sizes, int n_in,
                              void* d_out, int out_size, void* d_ws, size_t ws_size,
                              hipStream_t stream)
{
    const float* x    = (const float*)d_in[0];
    const int*   adj  = (const int*)d_in[1];
    const float* W    = (const float*)d_in[2];
    const float* bias = (const float*)d_in[3];
    const float* A    = (const float*)d_in[4];
    float* out = (float*)d_out;

    // workspace: WhbT (1 MB) | s1 (32 KB) | s2 (32 KB)
    char* ws = (char*)d_ws;
    __bf16* WhbT = (__bf16*)ws;
    float*  s1   = (float*)(ws + (size_t)FOUT * NN * sizeof(__bf16));
    float*  s2   = s1 + NN;

    gat_wh<<<dim3(512), dim3(256), 0, stream>>>(x, W, A, WhbT, s1, s2);
    gat_attn<<<dim3(NN / 16), dim3(256), 0, stream>>>(adj, WhbT, s1, s2, bias, out);
}